// Round 16
// baseline (136.264 us; speedup 1.0000x reference)
//
#include <hip/hip_runtime.h>
#include <math.h>

#define TQ   32768
#define HWSZ 16384
#define CC   64
#define HH   128
#define WW   128
#define C3   192
#define C4   256
#define KS   7

typedef _Float16 half2v __attribute__((ext_vector_type(2)));
typedef _Float16 half4v __attribute__((ext_vector_type(4)));
typedef _Float16 half8v __attribute__((ext_vector_type(8)));
typedef float    f32x4  __attribute__((ext_vector_type(4)));

#define MFMA16(a, b, c) __builtin_amdgcn_mfma_f32_16x16x32_f16((a), (b), (c), 0, 0, 0)

// ============ K1: LN1 + QKV GEMM + weight-f16 preconvert tail. grid 256 (R12, frozen) ============
__global__ __launch_bounds__(256) void k_qkvln(const float* __restrict__ x,
        const float* __restrict__ lnw, const float* __restrict__ lnb,
        const float* __restrict__ qw, const float* __restrict__ qb,
        const float* __restrict__ pw, const float* __restrict__ f1w,
        const float* __restrict__ f2w,
        _Float16* __restrict__ qkv16, _Float16* __restrict__ pw16,
        _Float16* __restrict__ f1w16, _Float16* __restrict__ f2w16) {
    __shared__ union {
        struct { __align__(16) _Float16 A[128 * 72]; __align__(16) _Float16 B[192 * 72]; } st;
        __align__(16) _Float16 outb[128 * 200];
    } u;
    __shared__ float ps1[256], ps2[256], m_s[128], r_s[128];
    __shared__ float w_s[64], b_s[64], bias_s[192];
    int tid = threadIdx.x;
    int t0 = blockIdx.x * 128;
    if (tid < 64) { w_s[tid] = lnw[tid]; b_s[tid] = lnb[tid]; }
    if (tid < 192) bias_s[tid] = qb[tid];
    int tok = tid & 127, cq = tid >> 7;
    int t = t0 + tok;
    int n = t >> 14, hw = t & (HWSZ - 1);
    const float* xr = x + ((size_t)n << 20) + hw;
    float v[32];
    float s = 0.f, s2 = 0.f;
#pragma unroll
    for (int e = 0; e < 32; ++e) {
        float f = xr[(cq * 32 + e) * HWSZ];
        v[e] = f; s += f; s2 += f * f;
    }
    ps1[tid] = s; ps2[tid] = s2;
    for (int i = tid; i < 3072; i += 256) {
        int jj = i >> 4, seg = i & 15;
        float4 v4 = *(const float4*)&qw[(size_t)jj * 64 + seg * 4];
        half4v h4 = { (_Float16)v4.x, (_Float16)v4.y, (_Float16)v4.z, (_Float16)v4.w };
        *(half4v*)&u.st.B[jj * 72 + seg * 4] = h4;
    }
    {
        int g = blockIdx.x * 256 + tid;
        if (g < 4096) pw16[g] = (_Float16)pw[g];
        else if (g < 20480) f1w16[g - 4096] = (_Float16)f1w[g - 4096];
        else if (g < 36864) f2w16[g - 20480] = (_Float16)f2w[g - 20480];
    }
    __syncthreads();
    if (tid < 128) {
        float ss = ps1[tid] + ps1[tid + 128];
        float qq = ps2[tid] + ps2[tid + 128];
        float m = ss * (1.f / 64.f);
        float var = qq * (1.f / 64.f) - m * m;
        m_s[tid] = m; r_s[tid] = rsqrtf(var + 1e-5f);
    }
    __syncthreads();
    {
        float m = m_s[tok], r = r_s[tok];
#pragma unroll
        for (int u8 = 0; u8 < 4; ++u8) {
            half8v o;
#pragma unroll
            for (int e = 0; e < 8; ++e) {
                int c = cq * 32 + u8 * 8 + e;
                o[e] = (_Float16)((v[u8 * 8 + e] - m) * r * w_s[c] + b_s[c]);
            }
            *(half8v*)&u.st.A[tok * 72 + cq * 32 + u8 * 8] = o;
        }
    }
    __syncthreads();
    int lane = tid & 63, wv = tid >> 6;
    int quad = lane >> 4, l16 = lane & 15;
    int mt0 = (wv & 1) * 64, nt0 = (wv >> 1) * 96;
    f32x4 acc[4][6];
#pragma unroll
    for (int mf = 0; mf < 4; ++mf)
#pragma unroll
        for (int nf = 0; nf < 6; ++nf) acc[mf][nf] = (f32x4){0.f, 0.f, 0.f, 0.f};
#pragma unroll
    for (int ks = 0; ks < 64; ks += 32) {
        half8v a[4], bfr[6];
#pragma unroll
        for (int mf = 0; mf < 4; ++mf)
            a[mf] = *(const half8v*)&u.st.A[(mt0 + mf * 16 + l16) * 72 + ks + quad * 8];
#pragma unroll
        for (int nf = 0; nf < 6; ++nf)
            bfr[nf] = *(const half8v*)&u.st.B[(nt0 + nf * 16 + l16) * 72 + ks + quad * 8];
#pragma unroll
        for (int mf = 0; mf < 4; ++mf)
#pragma unroll
            for (int nf = 0; nf < 6; ++nf) acc[mf][nf] = MFMA16(a[mf], bfr[nf], acc[mf][nf]);
    }
    __syncthreads();
    const float qscale = 0.17677669529663687f;
#pragma unroll
    for (int mf = 0; mf < 4; ++mf)
#pragma unroll
        for (int nf = 0; nf < 6; ++nf) {
            int j = nt0 + nf * 16 + l16;
            float bias = bias_s[j];
            float sc = (j < 64) ? qscale : 1.f;
#pragma unroll
            for (int r = 0; r < 4; ++r) {
                int tl = mt0 + mf * 16 + quad * 4 + r;
                u.outb[tl * 200 + j] = (_Float16)((acc[mf][nf][r] + bias) * sc);
            }
        }
    __syncthreads();
    for (int i = tid; i < 4096; i += 256) {
        int tk = i >> 5, rem = i & 31;
        if (rem < 24)
            *(half8v*)&qkv16[(size_t)(t0 + tk) * C3 + rem * 8] =
                *(const half8v*)&u.outb[tk * 200 + rem * 8];
    }
}

// ============ K2: attention + proj + residual + LN2 fused. grid 512 (R11, frozen) ============
__global__ __launch_bounds__(256) void k_attnproj(const _Float16* __restrict__ qkv16,
        const float* __restrict__ rpb,
        const _Float16* __restrict__ pw16, const float* __restrict__ pb,
        const float* __restrict__ x,
        const float* __restrict__ ln2w, const float* __restrict__ ln2b,
        _Float16* __restrict__ x2_16, _Float16* __restrict__ xn2_16) {
    __shared__ __align__(16) char smem[77704];
    _Float16* kv_s  = (_Float16*)smem;
    _Float16* q_s   = (_Float16*)(smem + 53312);
    _Float16* s_s   = (_Float16*)(smem + 63552);
    float*    rpb_s = (float*)(smem + 76352);
    float* x2t  = (float*)smem;
    float* ps1  = (float*)(smem + 20480);
    float* ps2  = (float*)(smem + 21504);
    float* m_s  = (float*)(smem + 22528);
    float* r_s  = (float*)(smem + 22784);
    float* w_s  = (float*)(smem + 23040);
    float* b_s  = (float*)(smem + 23296);
    float* pb_s = (float*)(smem + 23552);

    int tid = threadIdx.x;
    int bx = blockIdx.x;
    int n  = bx >> 8;
    int th = (bx >> 4) & 15, tw = bx & 15;
    int h0 = th * 8, w0 = tw * 8;
    int wr0 = min(max(h0 - 3, 0), HH - 14);
    int ww0 = min(max(w0 - 3, 0), WW - 14);
    int tbase = n << 14;
    int lane = tid & 63, wvi = tid >> 6;
    int quad = lane >> 4, l16 = lane & 15;

    for (int i = tid; i < 338; i += 256) rpb_s[i] = rpb[i];
    for (int i = tid; i < 196 * 16; i += 256) {
        int tok = i >> 4, u = i & 15;
        int wi = tok / 14, wj = tok - wi * 14;
        *(half8v*)&kv_s[tok * 136 + u * 8] = *(const half8v*)&qkv16[
            (size_t)(tbase + (wr0 + wi) * WW + ww0 + wj) * C3 + 64 + u * 8];
    }
    for (int i = tid; i < 64 * 8; i += 256) {
        int q = i >> 3, u = i & 7;
        int qg = tbase + (h0 + (q >> 3)) * WW + (w0 + (q & 7));
        *(half8v*)&q_s[q * 80 + u * 8] = *(const half8v*)&qkv16[(size_t)qg * C3 + u * 8];
    }
    __syncthreads();

    int c16 = tid & 1, z = (tid >> 1) & 1, q = tid >> 2;
    int qy = q >> 3, qx = q & 7;
    int h = h0 + qy, wc = w0 + qx;
    int sh = min(max(h - 3, 0), HH - KS);
    int sw = min(max(wc - 3, 0), WW - KS);
    int oh = sh - wr0, ow = sw - ww0;
    int dhp = h - sh + 6, dwp = wc - sw + 6;
    {
        const half8v* qp = (const half8v*)&q_s[q * 80 + z * 32];
        half8v q0 = qp[0], q1 = qp[1], q2 = qp[2], q3 = qp[3];
        int i7 = 0, j7 = c16;
        for (int nb = c16; nb < 49; nb += 2) {
            int tok = (oh + i7) * 14 + (ow + j7);
            const half8v* kp = (const half8v*)&kv_s[tok * 136 + z * 32];
            half2v acc2 = { (_Float16)0.f, (_Float16)0.f };
            half8v k0 = kp[0], k1 = kp[1], k2 = kp[2], k3 = kp[3];
            acc2 += (half2v){k0.s0, k0.s1} * (half2v){q0.s0, q0.s1};
            acc2 += (half2v){k0.s2, k0.s3} * (half2v){q0.s2, q0.s3};
            acc2 += (half2v){k0.s4, k0.s5} * (half2v){q0.s4, q0.s5};
            acc2 += (half2v){k0.s6, k0.s7} * (half2v){q0.s6, q0.s7};
            acc2 += (half2v){k1.s0, k1.s1} * (half2v){q1.s0, q1.s1};
            acc2 += (half2v){k1.s2, k1.s3} * (half2v){q1.s2, q1.s3};
            acc2 += (half2v){k1.s4, k1.s5} * (half2v){q1.s4, q1.s5};
            acc2 += (half2v){k1.s6, k1.s7} * (half2v){q1.s6, q1.s7};
            acc2 += (half2v){k2.s0, k2.s1} * (half2v){q2.s0, q2.s1};
            acc2 += (half2v){k2.s2, k2.s3} * (half2v){q2.s2, q2.s3};
            acc2 += (half2v){k2.s4, k2.s5} * (half2v){q2.s4, q2.s5};
            acc2 += (half2v){k2.s6, k2.s7} * (half2v){q2.s6, q2.s7};
            acc2 += (half2v){k3.s0, k3.s1} * (half2v){q3.s0, q3.s1};
            acc2 += (half2v){k3.s2, k3.s3} * (half2v){q3.s2, q3.s3};
            acc2 += (half2v){k3.s4, k3.s5} * (half2v){q3.s4, q3.s5};
            acc2 += (half2v){k3.s6, k3.s7} * (half2v){q3.s6, q3.s7};
            float s = (float)acc2.x + (float)acc2.y
                    + rpb_s[(z * 13 + (dhp - i7)) * 13 + (dwp - j7)];
            s_s[(q * 2 + z) * 50 + nb] = (_Float16)s;
            j7 += 2;
            if (j7 >= 7) { j7 -= 7; ++i7; }
        }
    }
    __syncthreads();

    if (tid < 128) {
        _Float16* sp = &s_s[tid * 50];
        float mx = -1e30f;
        for (int i = 0; i < 49; ++i) mx = fmaxf(mx, (float)sp[i]);
        float sum = 0.f;
        for (int i = 0; i < 49; ++i) {
            float e = __expf((float)sp[i] - mx);
            sum += e;
            sp[i] = (_Float16)e;
        }
        float inv = 1.f / sum;
        for (int i = 0; i < 49; ++i) sp[i] = (_Float16)((float)sp[i] * inv);
    }
    __syncthreads();

    {
        const _Float16* pp = &s_s[(q * 2 + z) * 50];
        half2v acc[8];
#pragma unroll
        for (int j = 0; j < 8; ++j) acc[j] = (half2v){ (_Float16)0.f, (_Float16)0.f };
        int i7 = 0, j7 = 0;
        for (int nb = 0; nb < 49; ++nb) {
            int tok = (oh + i7) * 14 + (ow + j7);
            _Float16 p = pp[nb];
            half2v p2 = { p, p };
            const half8v* vp = (const half8v*)&kv_s[tok * 136 + 64 + z * 32 + c16 * 16];
            half8v v0 = vp[0], v1 = vp[1];
            acc[0] += (half2v){v0.s0, v0.s1} * p2;
            acc[1] += (half2v){v0.s2, v0.s3} * p2;
            acc[2] += (half2v){v0.s4, v0.s5} * p2;
            acc[3] += (half2v){v0.s6, v0.s7} * p2;
            acc[4] += (half2v){v1.s0, v1.s1} * p2;
            acc[5] += (half2v){v1.s2, v1.s3} * p2;
            acc[6] += (half2v){v1.s4, v1.s5} * p2;
            acc[7] += (half2v){v1.s6, v1.s7} * p2;
            ++j7;
            if (j7 == 7) { j7 = 0; ++i7; }
        }
        _Float16* op = q_s + q * 72 + z * 32 + c16 * 16;
        half8v o0 = {acc[0].x, acc[0].y, acc[1].x, acc[1].y, acc[2].x, acc[2].y, acc[3].x, acc[3].y};
        half8v o1 = {acc[4].x, acc[4].y, acc[5].x, acc[5].y, acc[6].x, acc[6].y, acc[7].x, acc[7].y};
        *(half8v*)op = o0;
        *(half8v*)(op + 8) = o1;
    }
    __syncthreads();
    for (int i = tid; i < 512; i += 256) {
        int jj = i >> 3, c8 = i & 7;
        *(half8v*)&s_s[jj * 72 + c8 * 8] = *(const half8v*)&pw16[jj * 64 + c8 * 8];
    }
    if (tid < 64) { w_s[tid] = ln2w[tid]; b_s[tid] = ln2b[tid]; pb_s[tid] = pb[tid]; }
    __syncthreads();
    {
        int mt0 = wvi * 16;
        f32x4 acc2[4];
#pragma unroll
        for (int nf = 0; nf < 4; ++nf) acc2[nf] = (f32x4){0.f, 0.f, 0.f, 0.f};
#pragma unroll
        for (int ks = 0; ks < 64; ks += 32) {
            half8v a = *(const half8v*)&q_s[(mt0 + l16) * 72 + ks + quad * 8];
            half8v bfr[4];
#pragma unroll
            for (int nf = 0; nf < 4; ++nf)
                bfr[nf] = *(const half8v*)&s_s[(nf * 16 + l16) * 72 + ks + quad * 8];
#pragma unroll
            for (int nf = 0; nf < 4; ++nf) acc2[nf] = MFMA16(a, bfr[nf], acc2[nf]);
        }
        __syncthreads();
        int tl0 = mt0 + quad * 4;
        int hwl = (h0 + (tl0 >> 3)) * WW + w0 + (tl0 & 7);
#pragma unroll
        for (int nf = 0; nf < 4; ++nf) {
            int j = nf * 16 + l16;
            float bias = pb_s[j];
            float4 rx = *(const float4*)&x[((size_t)(n * CC + j) << 14) + hwl];
#pragma unroll
            for (int r = 0; r < 4; ++r)
                x2t[(tl0 + r) * 68 + j] = acc2[nf][r] + bias + ((const float*)&rx)[r];
        }
    }
    __syncthreads();
    int tok = tid & 63, cq = tid >> 6;
    {
        float s = 0.f, s2 = 0.f;
#pragma unroll
        for (int e = 0; e < 16; ++e) {
            float f = x2t[tok * 68 + cq * 16 + e];
            s += f; s2 += f * f;
        }
        ps1[tid] = s; ps2[tid] = s2;
    }
    __syncthreads();
    if (tid < 64) {
        float ss = ps1[tid] + ps1[64 + tid] + ps1[128 + tid] + ps1[192 + tid];
        float qq = ps2[tid] + ps2[64 + tid] + ps2[128 + tid] + ps2[192 + tid];
        float m = ss * (1.f / 64.f);
        float var = qq * (1.f / 64.f) - m * m;
        m_s[tid] = m; r_s[tid] = rsqrtf(var + 1e-5f);
    }
    __syncthreads();
    {
        float m = m_s[tok], r = r_s[tok];
        int qg = tbase + (h0 + (tok >> 3)) * WW + (w0 + (tok & 7));
        half8v hv0, hv1, nv0, nv1;
#pragma unroll
        for (int e = 0; e < 8; ++e) {
            int c = cq * 16 + e;
            float f = x2t[tok * 68 + c];
            hv0[e] = (_Float16)f;
            nv0[e] = (_Float16)((f - m) * r * w_s[c] + b_s[c]);
        }
#pragma unroll
        for (int e = 0; e < 8; ++e) {
            int c = cq * 16 + 8 + e;
            float f = x2t[tok * 68 + c];
            hv1[e] = (_Float16)f;
            nv1[e] = (_Float16)((f - m) * r * w_s[c] + b_s[c]);
        }
        size_t base = (size_t)qg * 64 + cq * 16;
        *(half8v*)&x2_16[base] = hv0;  *(half8v*)&x2_16[base + 8] = hv1;
        *(half8v*)&xn2_16[base] = nv0; *(half8v*)&xn2_16[base + 8] = nv1;
    }
}

// ============ K3: MLP v6 — grid 2048, 16-token tiles, ~9KB LDS -> 8 blocks/CU ============
__global__ __launch_bounds__(256) void k_mlp(const _Float16* __restrict__ xn2,
        const _Float16* __restrict__ x2_16,
        const _Float16* __restrict__ f1w16, const float* __restrict__ f1b,
        const _Float16* __restrict__ f2w16, const float* __restrict__ f2b,
        float* __restrict__ out) {
    __shared__ union {
        __align__(16) _Float16 H[16 * 264];             // 8.4 KB
        float tr[64 * 20];                              // 5.1 KB
    } u;
    __shared__ float f1b_s[256], f2b_s[64];
    int tid = threadIdx.x;
    int t0 = blockIdx.x * 16;
    int lane = tid & 63, wv = tid >> 6;
    int quad = lane >> 4, l16 = lane & 15;
    f1b_s[tid] = f1b[tid];
    if (tid < 64) f2b_s[tid] = f2b[tid];
    __syncthreads();
    // ---- fc1: wave wv owns 64 j cols; tile 16t x 64j, 8 MFMA/wave ----
    {
        int jt0 = wv * 64;
        f32x4 acc[4];
#pragma unroll
        for (int nf = 0; nf < 4; ++nf) acc[nf] = (f32x4){0.f, 0.f, 0.f, 0.f};
#pragma unroll
        for (int ks = 0; ks < 64; ks += 32) {
            half8v a = *(const half8v*)&xn2[(size_t)(t0 + l16) * 64 + ks + quad * 8];
            half8v bfr[4];
#pragma unroll
            for (int nf = 0; nf < 4; ++nf)
                bfr[nf] = *(const half8v*)&f1w16[(size_t)(jt0 + nf * 16 + l16) * 64 + ks + quad * 8];
#pragma unroll
            for (int nf = 0; nf < 4; ++nf) acc[nf] = MFMA16(a, bfr[nf], acc[nf]);
        }
#pragma unroll
        for (int nf = 0; nf < 4; ++nf) {
            int jl = jt0 + nf * 16 + l16;
            float bias = f1b_s[jl];
#pragma unroll
            for (int r = 0; r < 4; ++r) {
                int tl = quad * 4 + r;
                float vv = acc[nf][r] + bias;
                float g = 0.5f * vv * (1.f + erff(vv * 0.70710678118654752f));
                u.H[tl * 264 + jl] = (_Float16)g;
            }
        }
    }
    __syncthreads();   // H complete
    // ---- fc2: wave wv owns 16 j cols; tile 16t x 16j, K=256, 8 MFMA ----
    int j16 = wv * 16;
    f32x4 acc2 = (f32x4){0.f, 0.f, 0.f, 0.f};
#pragma unroll
    for (int ks = 0; ks < 256; ks += 32) {
        half8v a = *(const half8v*)&u.H[l16 * 264 + ks + quad * 8];
        half8v bfr = *(const half8v*)&f2w16[(size_t)(j16 + l16) * 256 + ks + quad * 8];
        acc2 = MFMA16(a, bfr, acc2);
    }
    __syncthreads();   // all H reads done -> tr overwrite safe
    {
        int j = j16 + l16;
        float bias = f2b_s[j];
#pragma unroll
        for (int r = 0; r < 4; ++r) {
            int tl = quad * 4 + r;
            float v = acc2[r] + bias + (float)x2_16[(size_t)(t0 + tl) * 64 + j];
            u.tr[j * 20 + tl] = v;
        }
    }
    __syncthreads();
    int n = t0 >> 14, hw0 = t0 & (HWSZ - 1);
    {
        int j = tid >> 2, seg = tid & 3;
        float4 v = *(const float4*)&u.tr[j * 20 + seg * 4];
        *(float4*)&out[((size_t)(n * CC + j) << 14) + hw0 + seg * 4] = v;
    }
}

extern "C" void kernel_launch(void* const* d_in, const int* in_sizes, int n_in,
                              void* d_out, int out_size, void* d_ws, size_t ws_size,
                              hipStream_t stream) {
    const float* x      = (const float*)d_in[0];
    const float* qkv_w  = (const float*)d_in[1];
    const float* qkv_b  = (const float*)d_in[2];
    const float* proj_w = (const float*)d_in[3];
    const float* proj_b = (const float*)d_in[4];
    const float* rpb    = (const float*)d_in[5];
    const float* ln1_w  = (const float*)d_in[6];
    const float* ln1_b  = (const float*)d_in[7];
    const float* ln2_w  = (const float*)d_in[8];
    const float* ln2_b  = (const float*)d_in[9];
    const float* fc1_w  = (const float*)d_in[10];
    const float* fc1_b  = (const float*)d_in[11];
    const float* fc2_w  = (const float*)d_in[12];
    const float* fc2_b  = (const float*)d_in[13];
    float* out = (float*)d_out;
    char* ws = (char*)d_ws;

    _Float16* qkv16  = (_Float16*)(ws);                 // 12.58 MB [T][192]
    _Float16* x2_16  = (_Float16*)(ws + 12582912);      //  4.19 MB [T][64]
    _Float16* xn2_16 = (_Float16*)(ws + 16777216);      //  4.19 MB [T][64]
    _Float16* pw16   = (_Float16*)(ws + 20971520);      //  8 KB
    _Float16* f1w16  = (_Float16*)(ws + 20979712);      // 32 KB
    _Float16* f2w16  = (_Float16*)(ws + 21012480);      // 32 KB

    k_qkvln   <<<256,  256, 0, stream>>>(x, ln1_w, ln1_b, qkv_w, qkv_b,
                                         proj_w, fc1_w, fc2_w,
                                         qkv16, pw16, f1w16, f2w16);
    k_attnproj<<<512,  256, 0, stream>>>(qkv16, rpb, pw16, proj_b, x, ln2_w, ln2_b,
                                         x2_16, xn2_16);
    k_mlp     <<<2048, 256, 0, stream>>>(xn2_16, x2_16, f1w16, fc1_b, f2w16, fc2_b, out);
}

// Round 17
// 128.492 us; speedup vs baseline: 1.0605x; 1.0605x over previous
//
#include <hip/hip_runtime.h>
#include <math.h>

#define TQ   32768
#define HWSZ 16384
#define CC   64
#define HH   128
#define WW   128
#define C3   192
#define C4   256
#define KS   7

typedef _Float16 half2v __attribute__((ext_vector_type(2)));
typedef _Float16 half4v __attribute__((ext_vector_type(4)));
typedef _Float16 half8v __attribute__((ext_vector_type(8)));
typedef float    f32x4  __attribute__((ext_vector_type(4)));

#define MFMA16(a, b, c) __builtin_amdgcn_mfma_f32_16x16x32_f16((a), (b), (c), 0, 0, 0)

// ============ K1: LN1 + QKV GEMM + weight-f16 preconvert tail. grid 256 (R12, frozen) ============
__global__ __launch_bounds__(256) void k_qkvln(const float* __restrict__ x,
        const float* __restrict__ lnw, const float* __restrict__ lnb,
        const float* __restrict__ qw, const float* __restrict__ qb,
        const float* __restrict__ pw, const float* __restrict__ f1w,
        const float* __restrict__ f2w,
        _Float16* __restrict__ qkv16, _Float16* __restrict__ pw16,
        _Float16* __restrict__ f1w16, _Float16* __restrict__ f2w16) {
    __shared__ union {
        struct { __align__(16) _Float16 A[128 * 72]; __align__(16) _Float16 B[192 * 72]; } st;
        __align__(16) _Float16 outb[128 * 200];
    } u;
    __shared__ float ps1[256], ps2[256], m_s[128], r_s[128];
    __shared__ float w_s[64], b_s[64], bias_s[192];
    int tid = threadIdx.x;
    int t0 = blockIdx.x * 128;
    if (tid < 64) { w_s[tid] = lnw[tid]; b_s[tid] = lnb[tid]; }
    if (tid < 192) bias_s[tid] = qb[tid];
    int tok = tid & 127, cq = tid >> 7;
    int t = t0 + tok;
    int n = t >> 14, hw = t & (HWSZ - 1);
    const float* xr = x + ((size_t)n << 20) + hw;
    float v[32];
    float s = 0.f, s2 = 0.f;
#pragma unroll
    for (int e = 0; e < 32; ++e) {
        float f = xr[(cq * 32 + e) * HWSZ];
        v[e] = f; s += f; s2 += f * f;
    }
    ps1[tid] = s; ps2[tid] = s2;
    for (int i = tid; i < 3072; i += 256) {
        int jj = i >> 4, seg = i & 15;
        float4 v4 = *(const float4*)&qw[(size_t)jj * 64 + seg * 4];
        half4v h4 = { (_Float16)v4.x, (_Float16)v4.y, (_Float16)v4.z, (_Float16)v4.w };
        *(half4v*)&u.st.B[jj * 72 + seg * 4] = h4;
    }
    {
        int g = blockIdx.x * 256 + tid;
        if (g < 4096) pw16[g] = (_Float16)pw[g];
        else if (g < 20480) f1w16[g - 4096] = (_Float16)f1w[g - 4096];
        else if (g < 36864) f2w16[g - 20480] = (_Float16)f2w[g - 20480];
    }
    __syncthreads();
    if (tid < 128) {
        float ss = ps1[tid] + ps1[tid + 128];
        float qq = ps2[tid] + ps2[tid + 128];
        float m = ss * (1.f / 64.f);
        float var = qq * (1.f / 64.f) - m * m;
        m_s[tid] = m; r_s[tid] = rsqrtf(var + 1e-5f);
    }
    __syncthreads();
    {
        float m = m_s[tok], r = r_s[tok];
#pragma unroll
        for (int u8 = 0; u8 < 4; ++u8) {
            half8v o;
#pragma unroll
            for (int e = 0; e < 8; ++e) {
                int c = cq * 32 + u8 * 8 + e;
                o[e] = (_Float16)((v[u8 * 8 + e] - m) * r * w_s[c] + b_s[c]);
            }
            *(half8v*)&u.st.A[tok * 72 + cq * 32 + u8 * 8] = o;
        }
    }
    __syncthreads();
    int lane = tid & 63, wv = tid >> 6;
    int quad = lane >> 4, l16 = lane & 15;
    int mt0 = (wv & 1) * 64, nt0 = (wv >> 1) * 96;
    f32x4 acc[4][6];
#pragma unroll
    for (int mf = 0; mf < 4; ++mf)
#pragma unroll
        for (int nf = 0; nf < 6; ++nf) acc[mf][nf] = (f32x4){0.f, 0.f, 0.f, 0.f};
#pragma unroll
    for (int ks = 0; ks < 64; ks += 32) {
        half8v a[4], bfr[6];
#pragma unroll
        for (int mf = 0; mf < 4; ++mf)
            a[mf] = *(const half8v*)&u.st.A[(mt0 + mf * 16 + l16) * 72 + ks + quad * 8];
#pragma unroll
        for (int nf = 0; nf < 6; ++nf)
            bfr[nf] = *(const half8v*)&u.st.B[(nt0 + nf * 16 + l16) * 72 + ks + quad * 8];
#pragma unroll
        for (int mf = 0; mf < 4; ++mf)
#pragma unroll
            for (int nf = 0; nf < 6; ++nf) acc[mf][nf] = MFMA16(a[mf], bfr[nf], acc[mf][nf]);
    }
    __syncthreads();
    const float qscale = 0.17677669529663687f;
#pragma unroll
    for (int mf = 0; mf < 4; ++mf)
#pragma unroll
        for (int nf = 0; nf < 6; ++nf) {
            int j = nt0 + nf * 16 + l16;
            float bias = bias_s[j];
            float sc = (j < 64) ? qscale : 1.f;
#pragma unroll
            for (int r = 0; r < 4; ++r) {
                int tl = mt0 + mf * 16 + quad * 4 + r;
                u.outb[tl * 200 + j] = (_Float16)((acc[mf][nf][r] + bias) * sc);
            }
        }
    __syncthreads();
    for (int i = tid; i < 4096; i += 256) {
        int tk = i >> 5, rem = i & 31;
        if (rem < 24)
            *(half8v*)&qkv16[(size_t)(t0 + tk) * C3 + rem * 8] =
                *(const half8v*)&u.outb[tk * 200 + rem * 8];
    }
}

// ============ K2: attention + proj + LN2 + MLP fused (everything after qkv). grid 512 ============
__global__ __launch_bounds__(256) void k_attnprojmlp(const _Float16* __restrict__ qkv16,
        const float* __restrict__ rpb,
        const _Float16* __restrict__ pw16, const float* __restrict__ pb,
        const float* __restrict__ x,
        const float* __restrict__ ln2w, const float* __restrict__ ln2b,
        const _Float16* __restrict__ f1w16, const float* __restrict__ f1b,
        const _Float16* __restrict__ f2w16, const float* __restrict__ f2b,
        float* __restrict__ out) {
    __shared__ __align__(16) char smem[77704];
    _Float16* kv_s  = (_Float16*)smem;              // [196*136] until PV
    _Float16* q_s   = (_Float16*)(smem + 53312);    // q stage (stride 80) -> attn-out/proj-A (stride 72)
    _Float16* s_s   = (_Float16*)(smem + 63552);    // scores -> proj-B (stride 72)
    float*    rpb_s = (float*)(smem + 76352);
    // post-PV overlays:
    float* x2t  = (float*)smem;                     // [64*68] f32 @ 0..17408 (persists to end)
    float* ps1  = (float*)(smem + 20480);
    float* ps2  = (float*)(smem + 21504);
    float* m_s  = (float*)(smem + 22528);
    float* r_s  = (float*)(smem + 22784);
    float* w_s  = (float*)(smem + 23040);
    float* b_s  = (float*)(smem + 23296);
    float* pb_s = (float*)(smem + 23552);
    _Float16* H_s   = (_Float16*)(smem + 24576);    // [64*264] f16 @ 24576..58368 (kv+q_s free)
    _Float16* xn2_s = (_Float16*)(smem + 63552);    // [64*72] f16 (s_s free after proj GEMM)
    float* f1b_s = (float*)(smem + 72768);          // [256]
    float* f2b_s = (float*)(smem + 73792);          // [64]

    int tid = threadIdx.x;
    int bx = blockIdx.x;
    int n  = bx >> 8;
    int th = (bx >> 4) & 15, tw = bx & 15;
    int h0 = th * 8, w0 = tw * 8;
    int wr0 = min(max(h0 - 3, 0), HH - 14);
    int ww0 = min(max(w0 - 3, 0), WW - 14);
    int tbase = n << 14;
    int lane = tid & 63, wvi = tid >> 6;
    int quad = lane >> 4, l16 = lane & 15;

    for (int i = tid; i < 338; i += 256) rpb_s[i] = rpb[i];
    for (int i = tid; i < 196 * 16; i += 256) {
        int tok = i >> 4, u = i & 15;
        int wi = tok / 14, wj = tok - wi * 14;
        *(half8v*)&kv_s[tok * 136 + u * 8] = *(const half8v*)&qkv16[
            (size_t)(tbase + (wr0 + wi) * WW + ww0 + wj) * C3 + 64 + u * 8];
    }
    for (int i = tid; i < 64 * 8; i += 256) {
        int q = i >> 3, u = i & 7;
        int qg = tbase + (h0 + (q >> 3)) * WW + (w0 + (q & 7));
        *(half8v*)&q_s[q * 80 + u * 8] = *(const half8v*)&qkv16[(size_t)qg * C3 + u * 8];
    }
    __syncthreads();

    int c16 = tid & 1, z = (tid >> 1) & 1, q = tid >> 2;
    int qy = q >> 3, qx = q & 7;
    int h = h0 + qy, wc = w0 + qx;
    int sh = min(max(h - 3, 0), HH - KS);
    int sw = min(max(wc - 3, 0), WW - KS);
    int oh = sh - wr0, ow = sw - ww0;
    int dhp = h - sh + 6, dwp = wc - sw + 6;
    {
        const half8v* qp = (const half8v*)&q_s[q * 80 + z * 32];
        half8v q0 = qp[0], q1 = qp[1], q2 = qp[2], q3 = qp[3];
        int i7 = 0, j7 = c16;
        for (int nb = c16; nb < 49; nb += 2) {
            int tok = (oh + i7) * 14 + (ow + j7);
            const half8v* kp = (const half8v*)&kv_s[tok * 136 + z * 32];
            half2v acc2 = { (_Float16)0.f, (_Float16)0.f };
            half8v k0 = kp[0], k1 = kp[1], k2 = kp[2], k3 = kp[3];
            acc2 += (half2v){k0.s0, k0.s1} * (half2v){q0.s0, q0.s1};
            acc2 += (half2v){k0.s2, k0.s3} * (half2v){q0.s2, q0.s3};
            acc2 += (half2v){k0.s4, k0.s5} * (half2v){q0.s4, q0.s5};
            acc2 += (half2v){k0.s6, k0.s7} * (half2v){q0.s6, q0.s7};
            acc2 += (half2v){k1.s0, k1.s1} * (half2v){q1.s0, q1.s1};
            acc2 += (half2v){k1.s2, k1.s3} * (half2v){q1.s2, q1.s3};
            acc2 += (half2v){k1.s4, k1.s5} * (half2v){q1.s4, q1.s5};
            acc2 += (half2v){k1.s6, k1.s7} * (half2v){q1.s6, q1.s7};
            acc2 += (half2v){k2.s0, k2.s1} * (half2v){q2.s0, q2.s1};
            acc2 += (half2v){k2.s2, k2.s3} * (half2v){q2.s2, q2.s3};
            acc2 += (half2v){k2.s4, k2.s5} * (half2v){q2.s4, q2.s5};
            acc2 += (half2v){k2.s6, k2.s7} * (half2v){q2.s6, q2.s7};
            acc2 += (half2v){k3.s0, k3.s1} * (half2v){q3.s0, q3.s1};
            acc2 += (half2v){k3.s2, k3.s3} * (half2v){q3.s2, q3.s3};
            acc2 += (half2v){k3.s4, k3.s5} * (half2v){q3.s4, q3.s5};
            acc2 += (half2v){k3.s6, k3.s7} * (half2v){q3.s6, q3.s7};
            float s = (float)acc2.x + (float)acc2.y
                    + rpb_s[(z * 13 + (dhp - i7)) * 13 + (dwp - j7)];
            s_s[(q * 2 + z) * 50 + nb] = (_Float16)s;
            j7 += 2;
            if (j7 >= 7) { j7 -= 7; ++i7; }
        }
    }
    __syncthreads();

    if (tid < 128) {
        _Float16* sp = &s_s[tid * 50];
        float mx = -1e30f;
        for (int i = 0; i < 49; ++i) mx = fmaxf(mx, (float)sp[i]);
        float sum = 0.f;
        for (int i = 0; i < 49; ++i) {
            float e = __expf((float)sp[i] - mx);
            sum += e;
            sp[i] = (_Float16)e;
        }
        float inv = 1.f / sum;
        for (int i = 0; i < 49; ++i) sp[i] = (_Float16)((float)sp[i] * inv);
    }
    __syncthreads();

    // ---- PV -> attn out to q_s (proj A, stride 72) ----
    {
        const _Float16* pp = &s_s[(q * 2 + z) * 50];
        half2v acc[8];
#pragma unroll
        for (int j = 0; j < 8; ++j) acc[j] = (half2v){ (_Float16)0.f, (_Float16)0.f };
        int i7 = 0, j7 = 0;
        for (int nb = 0; nb < 49; ++nb) {
            int tok = (oh + i7) * 14 + (ow + j7);
            _Float16 p = pp[nb];
            half2v p2 = { p, p };
            const half8v* vp = (const half8v*)&kv_s[tok * 136 + 64 + z * 32 + c16 * 16];
            half8v v0 = vp[0], v1 = vp[1];
            acc[0] += (half2v){v0.s0, v0.s1} * p2;
            acc[1] += (half2v){v0.s2, v0.s3} * p2;
            acc[2] += (half2v){v0.s4, v0.s5} * p2;
            acc[3] += (half2v){v0.s6, v0.s7} * p2;
            acc[4] += (half2v){v1.s0, v1.s1} * p2;
            acc[5] += (half2v){v1.s2, v1.s3} * p2;
            acc[6] += (half2v){v1.s4, v1.s5} * p2;
            acc[7] += (half2v){v1.s6, v1.s7} * p2;
            ++j7;
            if (j7 == 7) { j7 = 0; ++i7; }
        }
        _Float16* op = q_s + q * 72 + z * 32 + c16 * 16;
        half8v o0 = {acc[0].x, acc[0].y, acc[1].x, acc[1].y, acc[2].x, acc[2].y, acc[3].x, acc[3].y};
        half8v o1 = {acc[4].x, acc[4].y, acc[5].x, acc[5].y, acc[6].x, acc[6].y, acc[7].x, acc[7].y};
        *(half8v*)op = o0;
        *(half8v*)(op + 8) = o1;
    }
    __syncthreads();
    // ---- stage proj B + LN2 params + fc biases ----
    for (int i = tid; i < 512; i += 256) {
        int jj = i >> 3, c8 = i & 7;
        *(half8v*)&s_s[jj * 72 + c8 * 8] = *(const half8v*)&pw16[jj * 64 + c8 * 8];
    }
    if (tid < 64) { w_s[tid] = ln2w[tid]; b_s[tid] = ln2b[tid]; pb_s[tid] = pb[tid]; }
    f1b_s[tid] = f1b[tid];
    if (tid < 64) f2b_s[tid] = f2b[tid];
    __syncthreads();
    // ---- proj GEMM + residual -> x2t (f32, LDS) ----
    {
        int mt0 = wvi * 16;
        f32x4 acc2[4];
#pragma unroll
        for (int nf = 0; nf < 4; ++nf) acc2[nf] = (f32x4){0.f, 0.f, 0.f, 0.f};
#pragma unroll
        for (int ks = 0; ks < 64; ks += 32) {
            half8v a = *(const half8v*)&q_s[(mt0 + l16) * 72 + ks + quad * 8];
            half8v bfr[4];
#pragma unroll
            for (int nf = 0; nf < 4; ++nf)
                bfr[nf] = *(const half8v*)&s_s[(nf * 16 + l16) * 72 + ks + quad * 8];
#pragma unroll
            for (int nf = 0; nf < 4; ++nf) acc2[nf] = MFMA16(a, bfr[nf], acc2[nf]);
        }
        __syncthreads();   // A/B reads done before x2t (kv region) overwrite + xn2_s (s_s) reuse
        int tl0 = mt0 + quad * 4;
        int hwl = (h0 + (tl0 >> 3)) * WW + w0 + (tl0 & 7);
#pragma unroll
        for (int nf = 0; nf < 4; ++nf) {
            int j = nf * 16 + l16;
            float bias = pb_s[j];
            float4 rx = *(const float4*)&x[((size_t)(n * CC + j) << 14) + hwl];
#pragma unroll
            for (int r = 0; r < 4; ++r)
                x2t[(tl0 + r) * 68 + j] = acc2[nf][r] + bias + ((const float*)&rx)[r];
        }
    }
    __syncthreads();
    // ---- LN2 stats ----
    int tok = tid & 63, cq = tid >> 6;
    {
        float s = 0.f, s2 = 0.f;
#pragma unroll
        for (int e = 0; e < 16; ++e) {
            float f = x2t[tok * 68 + cq * 16 + e];
            s += f; s2 += f * f;
        }
        ps1[tid] = s; ps2[tid] = s2;
    }
    __syncthreads();
    if (tid < 64) {
        float ss = ps1[tid] + ps1[64 + tid] + ps1[128 + tid] + ps1[192 + tid];
        float qq = ps2[tid] + ps2[64 + tid] + ps2[128 + tid] + ps2[192 + tid];
        float m = ss * (1.f / 64.f);
        float var = qq * (1.f / 64.f) - m * m;
        m_s[tid] = m; r_s[tid] = rsqrtf(var + 1e-5f);
    }
    __syncthreads();
    // ---- LN2 normalize -> xn2_s (LDS only, no global) ----
    {
        float m = m_s[tok], r = r_s[tok];
        half8v nv0, nv1;
#pragma unroll
        for (int e = 0; e < 8; ++e) {
            int c = cq * 16 + e;
            nv0[e] = (_Float16)((x2t[tok * 68 + c] - m) * r * w_s[c] + b_s[c]);
        }
#pragma unroll
        for (int e = 0; e < 8; ++e) {
            int c = cq * 16 + 8 + e;
            nv1[e] = (_Float16)((x2t[tok * 68 + c] - m) * r * w_s[c] + b_s[c]);
        }
        *(half8v*)&xn2_s[tok * 72 + cq * 16] = nv0;
        *(half8v*)&xn2_s[tok * 72 + cq * 16 + 8] = nv1;
    }
    __syncthreads();
    // ---- fc1: wave wvi owns 64 j-cols; A = xn2_s (LDS), B = f1w16 streamed; GELU -> H_s ----
    {
        int j0 = wvi * 64;
        f32x4 accm[4][4];
#pragma unroll
        for (int mf = 0; mf < 4; ++mf)
#pragma unroll
            for (int nf = 0; nf < 4; ++nf) accm[mf][nf] = (f32x4){0.f, 0.f, 0.f, 0.f};
#pragma unroll
        for (int ks = 0; ks < 64; ks += 32) {
            half8v a[4], bfr[4];
#pragma unroll
            for (int mf = 0; mf < 4; ++mf)
                a[mf] = *(const half8v*)&xn2_s[(mf * 16 + l16) * 72 + ks + quad * 8];
#pragma unroll
            for (int nf = 0; nf < 4; ++nf)
                bfr[nf] = *(const half8v*)&f1w16[(size_t)(j0 + nf * 16 + l16) * 64 + ks + quad * 8];
#pragma unroll
            for (int mf = 0; mf < 4; ++mf)
#pragma unroll
                for (int nf = 0; nf < 4; ++nf) accm[mf][nf] = MFMA16(a[mf], bfr[nf], accm[mf][nf]);
        }
#pragma unroll
        for (int mf = 0; mf < 4; ++mf)
#pragma unroll
            for (int nf = 0; nf < 4; ++nf) {
                int jl = j0 + nf * 16 + l16;
                float bias = f1b_s[jl];
#pragma unroll
                for (int r = 0; r < 4; ++r) {
                    int tl = mf * 16 + quad * 4 + r;
                    float vv = accm[mf][nf][r] + bias;
                    float g = 0.5f * vv * (1.f + erff(vv * 0.70710678118654752f));
                    H_s[tl * 264 + jl] = (_Float16)g;
                }
            }
    }
    __syncthreads();   // H complete
    // ---- fc2: wave tile 16t x 64j, K=256; H from LDS, W2 streamed; + residual from x2t ----
    {
        int mt = wvi * 16;
        f32x4 acc2[4];
#pragma unroll
        for (int nf = 0; nf < 4; ++nf) acc2[nf] = (f32x4){0.f, 0.f, 0.f, 0.f};
#pragma unroll
        for (int ks = 0; ks < 256; ks += 32) {
            half8v a = *(const half8v*)&H_s[(mt + l16) * 264 + ks + quad * 8];
            half8v bfr[4];
#pragma unroll
            for (int nf = 0; nf < 4; ++nf)
                bfr[nf] = *(const half8v*)&f2w16[(size_t)(nf * 16 + l16) * 256 + ks + quad * 8];
#pragma unroll
            for (int nf = 0; nf < 4; ++nf) acc2[nf] = MFMA16(a, bfr[nf], acc2[nf]);
        }
        float val[4][4];
#pragma unroll
        for (int nf = 0; nf < 4; ++nf) {
            int j = nf * 16 + l16;
            float bias = f2b_s[j];
#pragma unroll
            for (int r = 0; r < 4; ++r) {
                int tl = mt + quad * 4 + r;
                val[nf][r] = acc2[nf][r] + bias + x2t[tl * 68 + j];
            }
        }
        __syncthreads();   // all x2t reads done -> transpose overwrite safe
#pragma unroll
        for (int nf = 0; nf < 4; ++nf) {
            int j = nf * 16 + l16;
#pragma unroll
            for (int r = 0; r < 4; ++r) {
                int tl = mt + quad * 4 + r;
                x2t[j * 68 + tl] = val[nf][r];
            }
        }
    }
    __syncthreads();
    // ---- NCHW stores: channel j, 8x8 spatial tile rows of 8 ----
    for (int i = tid; i < 1024; i += 256) {
        int j = i >> 4, seg = i & 15;
        int tl0 = seg * 4;
        float4 v = *(const float4*)&x2t[j * 68 + tl0];
        *(float4*)&out[((size_t)(n * CC + j) << 14) + (h0 + (tl0 >> 3)) * WW + w0 + (tl0 & 7)] = v;
    }
}

extern "C" void kernel_launch(void* const* d_in, const int* in_sizes, int n_in,
                              void* d_out, int out_size, void* d_ws, size_t ws_size,
                              hipStream_t stream) {
    const float* x      = (const float*)d_in[0];
    const float* qkv_w  = (const float*)d_in[1];
    const float* qkv_b  = (const float*)d_in[2];
    const float* proj_w = (const float*)d_in[3];
    const float* proj_b = (const float*)d_in[4];
    const float* rpb    = (const float*)d_in[5];
    const float* ln1_w  = (const float*)d_in[6];
    const float* ln1_b  = (const float*)d_in[7];
    const float* ln2_w  = (const float*)d_in[8];
    const float* ln2_b  = (const float*)d_in[9];
    const float* fc1_w  = (const float*)d_in[10];
    const float* fc1_b  = (const float*)d_in[11];
    const float* fc2_w  = (const float*)d_in[12];
    const float* fc2_b  = (const float*)d_in[13];
    float* out = (float*)d_out;
    char* ws = (char*)d_ws;

    _Float16* qkv16 = (_Float16*)(ws);                  // 12.58 MB [T][192]
    _Float16* pw16  = (_Float16*)(ws + 12582912);       //  8 KB
    _Float16* f1w16 = (_Float16*)(ws + 12591104);       // 32 KB
    _Float16* f2w16 = (_Float16*)(ws + 12623872);       // 32 KB

    k_qkvln      <<<256, 256, 0, stream>>>(x, ln1_w, ln1_b, qkv_w, qkv_b,
                                           proj_w, fc1_w, fc2_w,
                                           qkv16, pw16, f1w16, f2w16);
    k_attnprojmlp<<<512, 256, 0, stream>>>(qkv16, rpb, pw16, proj_b, x, ln2_w, ln2_b,
                                           f1w16, fc1_b, f2w16, fc2_b, out);
}